// Round 1
// baseline (898.453 us; speedup 1.0000x reference)
//
#include <hip/hip_runtime.h>
#include <hip/hip_bf16.h>

// Conv2d: x(32,128,56,56) fp32, w(256,128,3,3) fp32, bias(256), stride1 pad1.
// Implicit GEMM: M=C_out=256, N=32*56*56=100352, K=128*9=1152.
// bf16 MFMA 16x16x32, 128x128 block tile, 256 threads (4 waves, 2x2 of 64x64).

#define CIN   128
#define HH    56
#define WW    56
#define COUT  256
#define HW    (HH * WW)        // 3136
#define KK    (CIN * 9)        // 1152
#define BK    32
#define BM    128
#define BN    128
#define LSTR  40               // padded LDS row stride in bf16 (80B, 16B-aligned)

typedef __bf16 bf16x8 __attribute__((ext_vector_type(8)));
typedef float  f32x4  __attribute__((ext_vector_type(4)));

__global__ __launch_bounds__(256) void conv_igemm(
    const float* __restrict__ xin,
    const float* __restrict__ wgt,
    const float* __restrict__ bias,
    float* __restrict__ out)
{
    __shared__ unsigned short Alds[BM][LSTR];   // A[co_local][k_local]
    __shared__ unsigned short Blds[BN][LSTR];   // B^T: [p_local][k_local]

    const int tid    = threadIdx.x;
    const int bm     = blockIdx.x & 1;          // 2 blocks over C_out
    const int bn     = blockIdx.x >> 1;         // 784 blocks over positions
    const int pbase  = bn * BN;
    const int cobase = bm * BM;

    const int lane = tid & 63;
    const int wv   = tid >> 6;
    const int wm   = wv & 1;                    // wave m-coord (2x2)
    const int wn   = wv >> 1;                   // wave n-coord
    const int l15  = lane & 15;
    const int quad = lane >> 4;

    // --- B-staging coords: thread owns one position p, 16 consecutive k ---
    const int pl    = tid & 127;                // p_local
    const int khalf = tid >> 7;                 // wave-uniform: waves 0,1 -> 0; 2,3 -> 1
    const int p     = pbase + pl;
    const int n_img = p / HW;
    const int rem   = p - n_img * HW;
    const int ypos  = rem / WW;
    const int xpos  = rem - ypos * WW;
    const float* xb = xin + (size_t)n_img * (CIN * HW) + ypos * WW + xpos;

    f32x4 acc[4][4];
    #pragma unroll
    for (int i = 0; i < 4; ++i)
        #pragma unroll
        for (int j = 0; j < 4; ++j)
            acc[i][j] = (f32x4){0.f, 0.f, 0.f, 0.f};

    for (int kb = 0; kb < KK; kb += BK) {
        __syncthreads();

        // ---- stage A (weights): 128 co x 32 k, fp32 -> bf16 (truncate) ----
        // A[co][k] = wgt[co*1152 + k] (weight layout is exactly (C_out, K)).
        #pragma unroll
        for (int i = 0; i < 4; ++i) {
            int g   = tid + 256 * i;
            int row = g >> 3;                   // 0..127
            int c4  = g & 7;                    // float4 index within 32-col row
            const float4 v = *(const float4*)(wgt + (size_t)(cobase + row) * KK + kb + c4 * 4);
            unsigned lo = (__float_as_uint(v.y) & 0xFFFF0000u) | (__float_as_uint(v.x) >> 16);
            unsigned hi = (__float_as_uint(v.w) & 0xFFFF0000u) | (__float_as_uint(v.z) >> 16);
            *(uint2*)&Alds[row][c4 * 4] = make_uint2(lo, hi);
        }

        // ---- stage B (im2col): 32 k x 128 p, stored transposed [p][k] ----
        // k -> (ci, r, s) decode is wave-uniform (khalf is per-wave constant):
        // force SALU via readfirstlane. Per-lane work: iy/ix add+cmp, masked load.
        const int ksc = __builtin_amdgcn_readfirstlane(kb + khalf * 16);
        unsigned bpk[8];
        #pragma unroll
        for (int jj = 0; jj < 8; ++jj) {
            float v01[2];
            #pragma unroll
            for (int h = 0; h < 2; ++h) {
                int k  = ksc + 2 * jj + h;
                int ci = k / 9;
                int rs = k - ci * 9;
                int r  = rs / 3;
                int s  = rs - r * 3;
                int iy = ypos + r - 1;
                int ix = xpos + s - 1;
                float val = 0.f;
                if ((unsigned)iy < (unsigned)HH && (unsigned)ix < (unsigned)WW)
                    val = xb[ci * HW + (r - 1) * WW + (s - 1)];
                v01[h] = val;
            }
            bpk[jj] = (__float_as_uint(v01[1]) & 0xFFFF0000u) | (__float_as_uint(v01[0]) >> 16);
        }
        *(uint4*)&Blds[pl][khalf * 16]     = make_uint4(bpk[0], bpk[1], bpk[2], bpk[3]);
        *(uint4*)&Blds[pl][khalf * 16 + 8] = make_uint4(bpk[4], bpk[5], bpk[6], bpk[7]);

        __syncthreads();

        // ---- MFMA: A frag A[m=lane&15][k=quad*8+j], B frag B[k][n=lane&15] ----
        bf16x8 af[4], bfg[4];
        #pragma unroll
        for (int mt = 0; mt < 4; ++mt)
            af[mt] = *(const bf16x8*)&Alds[wm * 64 + mt * 16 + l15][quad * 8];
        #pragma unroll
        for (int nt = 0; nt < 4; ++nt)
            bfg[nt] = *(const bf16x8*)&Blds[wn * 64 + nt * 16 + l15][quad * 8];
        #pragma unroll
        for (int mt = 0; mt < 4; ++mt)
            #pragma unroll
            for (int nt = 0; nt < 4; ++nt)
                acc[mt][nt] = __builtin_amdgcn_mfma_f32_16x16x32_bf16(af[mt], bfg[nt], acc[mt][nt], 0, 0, 0);
    }

    // ---- epilogue: D[m = quad*4+reg][n = lane&15]; out is (N, C_out, H, W) ----
    #pragma unroll
    for (int nt = 0; nt < 4; ++nt) {
        int pp = pbase + wn * 64 + nt * 16 + l15;
        int n2 = pp / HW;
        int r2 = pp - n2 * HW;
        float* ob = out + (size_t)n2 * (COUT * HW) + r2;
        #pragma unroll
        for (int mt = 0; mt < 4; ++mt) {
            int co = cobase + wm * 64 + mt * 16 + quad * 4;
            const float4 bv = *(const float4*)(bias + co);
            f32x4 a = acc[mt][nt];
            ob[(size_t)(co + 0) * HW] = a[0] + bv.x;
            ob[(size_t)(co + 1) * HW] = a[1] + bv.y;
            ob[(size_t)(co + 2) * HW] = a[2] + bv.z;
            ob[(size_t)(co + 3) * HW] = a[3] + bv.w;
        }
    }
}

extern "C" void kernel_launch(void* const* d_in, const int* in_sizes, int n_in,
                              void* d_out, int out_size, void* d_ws, size_t ws_size,
                              hipStream_t stream) {
    const float* x = (const float*)d_in[0];
    const float* w = (const float*)d_in[1];
    const float* b = (const float*)d_in[2];
    float* o = (float*)d_out;
    const int NP = 32 * HW;                      // 100352, exactly 784 * BN
    const int nblocks = (NP / BN) * (COUT / BM); // 784 * 2 = 1568
    conv_igemm<<<dim3(nblocks), dim3(256), 0, stream>>>(x, w, b, o);
}

// Round 2
// 215.130 us; speedup vs baseline: 4.1763x; 4.1763x over previous
//
#include <hip/hip_runtime.h>
#include <hip/hip_bf16.h>

// Conv2d 3x3 s1p1: x(32,128,56,56) f32, w(256,128,3,3) f32, bias(256) -> (32,256,56,56) f32.
// Strategy: pre-pass to NHWC-bf16 with zero halo (d_ws), weights to Wt[9][co][ci] bf16.
// Main: tap-structured implicit GEMM, 128x128 tile, BK=64 (tap x ci-half),
// global_load_lds(16B) staging with XOR swizzle, mfma_f32_16x16x32_bf16.

#define CIN   128
#define HH    56
#define WW    56
#define COUT  256
#define HW    3136
#define NIMG  32
#define NP    (NIMG * HW)            // 100352 = 784 * 128
#define XPW   58
#define XPIX  (XPW * XPW)            // 3364
#define XPAD_BYTES (NIMG * XPIX * CIN * 2)   // 27,566,080
#define WT_OFF     XPAD_BYTES                 // 256B-aligned

typedef __bf16 bf16x8 __attribute__((ext_vector_type(8)));
typedef float  f32x4  __attribute__((ext_vector_type(4)));

#define GLD16(g, l) __builtin_amdgcn_global_load_lds( \
    (const __attribute__((address_space(1))) void*)(g), \
    (__attribute__((address_space(3))) void*)(l), 16, 0, 0)

// ---- pre-pass 1: x NCHW f32 -> xpad NHWC bf16 with 1-px halo (halo pre-zeroed by memset)
__global__ __launch_bounds__(128) void prep_x(const float* __restrict__ x,
                                              __hip_bfloat16* __restrict__ xp) {
    const int b = blockIdx.x;            // 32*56 blocks
    const int n = b / HH;
    const int y = b - n * HH;
    const int ci = threadIdx.x;          // 0..127
    const float* src = x + ((size_t)(n * CIN + ci) * HW) + y * WW;
    __hip_bfloat16* dst = xp + ((size_t)(n * XPIX + (y + 1) * XPW + 1)) * CIN + ci;
    // writes: 128 lanes consecutive ci -> 256B coalesced; reads: per-lane row stream, L1-reused
    for (int xx = 0; xx < WW; ++xx)
        dst[(size_t)xx * CIN] = __float2bfloat16(src[xx]);
}

// ---- pre-pass 2: w (co,ci,3,3) f32 -> Wt[tap][co][ci] bf16
__global__ __launch_bounds__(256) void prep_w(const float* __restrict__ w,
                                              __hip_bfloat16* __restrict__ wt) {
    const int co = blockIdx.x * 2 + (threadIdx.x >> 7);   // 128 blocks
    const int ci = threadIdx.x & 127;
    const float* src = w + (size_t)(co * CIN + ci) * 9;
    #pragma unroll
    for (int t = 0; t < 9; ++t)
        wt[(size_t)t * (COUT * CIN) + co * CIN + ci] = __float2bfloat16(src[t]);
}

// ---- main: implicit GEMM over taps
__global__ __launch_bounds__(256) void conv_main(
    const char* __restrict__ xpb,        // xpad bytes
    const char* __restrict__ wtb,        // Wt bytes
    const float* __restrict__ bias,
    float* __restrict__ out)
{
    // swizzled chunk tiles: row = co (A) or p (B), 8 x 16B segs per 64-ci half,
    // LDS seg s of row R holds global seg s ^ (R & 7).
    __shared__ __align__(16) char Alds[16384];
    __shared__ __align__(16) char Blds[16384];

    const int tid  = threadIdx.x;
    const int l    = tid & 63;
    const int wv   = tid >> 6;
    const int wm   = wv & 1;
    const int wn   = wv >> 1;
    const int l15  = l & 15;
    const int quad = l >> 4;
    const int lr   = l >> 3;             // 0..7 : row within 8-row group
    const int ls   = l & 7;              // 0..7 : LDS seg this lane fills
    const int sg   = ls ^ lr;            // global seg to fetch (XOR swizzle)

    const int bm = blockIdx.x & 1;       // pair-adjacent co-blocks share B -> L2 locality
    const int bn = blockIdx.x >> 1;
    const int pbase  = bn * 128;
    const int cobase = bm * 128;

    // per-thread staging byte offsets (constant across all 18 K-steps)
    unsigned aoff[4], boff[4];
    #pragma unroll
    for (int j = 0; j < 4; ++j) {
        const int rowl = (wv * 4 + j) * 8 + lr;          // 0..127
        aoff[j] = (unsigned)((cobase + rowl) * 256 + sg * 16);
        const int p   = pbase + rowl;
        const int n   = p / HW;
        const int rem = p - n * HW;
        const int y   = rem / WW;
        const int x   = rem - y * WW;
        boff[j] = (unsigned)((n * XPIX + y * XPW + x) * 256 + sg * 16);
    }

    f32x4 acc[4][4];
    #pragma unroll
    for (int i = 0; i < 4; ++i)
        #pragma unroll
        for (int j = 0; j < 4; ++j)
            acc[i][j] = (f32x4){0.f, 0.f, 0.f, 0.f};

    #pragma unroll
    for (int t = 0; t < 9; ++t) {
        const int r = t / 3;
        const int s = t - 3 * r;
        #pragma unroll
        for (int hf = 0; hf < 2; ++hf) {
            const unsigned wo = (unsigned)(t * 65536 + hf * 128);          // Wt tap plane + ci-half
            const unsigned bo = (unsigned)((r * XPW + s) * 256 + hf * 128); // tap shift + ci-half

            __syncthreads();   // previous step's frag reads done before overwrite
            #pragma unroll
            for (int j = 0; j < 4; ++j) {
                GLD16(wtb + wo + aoff[j], Alds + (wv * 4 + j) * 1024);
                GLD16(xpb + bo + boff[j], Blds + (wv * 4 + j) * 1024);
            }
            __syncthreads();   // staging DMA drained (vmcnt) + all waves arrived

            #pragma unroll
            for (int kg = 0; kg < 2; ++kg) {
                bf16x8 af[4], bfr[4];
                #pragma unroll
                for (int mt = 0; mt < 4; ++mt) {
                    const int row  = wm * 64 + mt * 16 + l15;
                    const int segl = (kg * 4 + quad) ^ (row & 7);
                    af[mt] = *(const bf16x8*)(Alds + row * 128 + segl * 16);
                }
                #pragma unroll
                for (int nt = 0; nt < 4; ++nt) {
                    const int row  = wn * 64 + nt * 16 + l15;
                    const int segl = (kg * 4 + quad) ^ (row & 7);
                    bfr[nt] = *(const bf16x8*)(Blds + row * 128 + segl * 16);
                }
                #pragma unroll
                for (int mt = 0; mt < 4; ++mt)
                    #pragma unroll
                    for (int nt = 0; nt < 4; ++nt)
                        acc[mt][nt] = __builtin_amdgcn_mfma_f32_16x16x32_bf16(
                            af[mt], bfr[nt], acc[mt][nt], 0, 0, 0);
            }
        }
    }

    // epilogue: D[m = quad*4+reg][n = l15]; out (N, C_out, H, W)
    #pragma unroll
    for (int nt = 0; nt < 4; ++nt) {
        const int pp = pbase + wn * 64 + nt * 16 + l15;
        const int n2 = pp / HW;
        const int r2 = pp - n2 * HW;
        float* ob = out + (size_t)n2 * (COUT * HW) + r2;
        #pragma unroll
        for (int mt = 0; mt < 4; ++mt) {
            const int co = cobase + wm * 64 + mt * 16 + quad * 4;
            const float4 bv = *(const float4*)(bias + co);
            f32x4 a = acc[mt][nt];
            ob[(size_t)(co + 0) * HW] = a[0] + bv.x;
            ob[(size_t)(co + 1) * HW] = a[1] + bv.y;
            ob[(size_t)(co + 2) * HW] = a[2] + bv.z;
            ob[(size_t)(co + 3) * HW] = a[3] + bv.w;
        }
    }
}

extern "C" void kernel_launch(void* const* d_in, const int* in_sizes, int n_in,
                              void* d_out, int out_size, void* d_ws, size_t ws_size,
                              hipStream_t stream) {
    const float* x = (const float*)d_in[0];
    const float* w = (const float*)d_in[1];
    const float* b = (const float*)d_in[2];
    char* ws = (char*)d_ws;                      // needs >= 28.2 MB
    __hip_bfloat16* xp = (__hip_bfloat16*)ws;
    __hip_bfloat16* wt = (__hip_bfloat16*)(ws + WT_OFF);

    hipMemsetAsync(ws, 0, XPAD_BYTES, stream);   // zero halo (interior overwritten)
    prep_x<<<dim3(NIMG * HH), dim3(128), 0, stream>>>(x, xp);
    prep_w<<<dim3(128), dim3(256), 0, stream>>>(w, wt);
    conv_main<<<dim3((NP / 128) * 2), dim3(256), 0, stream>>>(
        (const char*)xp, (const char*)wt, b, (float*)d_out);
}

// Round 3
// 212.927 us; speedup vs baseline: 4.2195x; 1.0103x over previous
//
#include <hip/hip_runtime.h>
#include <hip/hip_bf16.h>

// Conv2d 3x3 s1p1: x(32,128,56,56) f32, w(256,128,3,3) f32, bias(256) -> (32,256,56,56) f32.
// R3: prep_x rewritten (LDS transpose, coalesced stores, self-written halo, no memset);
// conv_main BK=128 (9 tap-steps, 64KB LDS, 64 MFMA/wave per drain); XCD-pair swizzle.

#define CIN   128
#define HH    56
#define WW    56
#define COUT  256
#define HW    3136
#define NIMG  32
#define NP    (NIMG * HW)            // 100352 = 784 * 128
#define XPW   58
#define XPIX  (XPW * XPW)            // 3364
#define XPAD_BYTES (NIMG * XPIX * CIN * 2)   // 27,566,080
#define WT_OFF     XPAD_BYTES

typedef __bf16 bf16x8 __attribute__((ext_vector_type(8)));
typedef float  f32x4  __attribute__((ext_vector_type(4)));

#define GLD16(g, l) __builtin_amdgcn_global_load_lds( \
    (const __attribute__((address_space(1))) void*)(g), \
    (__attribute__((address_space(3))) void*)(l), 16, 0, 0)

__device__ __forceinline__ unsigned pack_bf16(float a, float b) {
    // [b:a] with round-to-nearest-even via __float2bfloat16 would cost VALU; truncation
    // matched threshold fine in R1/R2 (absmax 0.03 vs 0.129) -> keep truncation.
    return (__float_as_uint(b) & 0xFFFF0000u) | (__float_as_uint(a) >> 16);
}

// ---- pre-pass 1: x NCHW f32 -> xpad NHWC bf16 with 1-px halo; writes own halo zeros.
__global__ __launch_bounds__(128) void prep_x(const float* __restrict__ x,
                                              __hip_bfloat16* __restrict__ xp) {
    __shared__ unsigned short t[HH * CIN];   // [x][ci], 14336 B
    const int b  = blockIdx.x;               // 32*56
    const int n  = b / HH;
    const int y  = b - n * HH;
    const int ci = threadIdx.x;              // 0..127

    const float* src = x + ((size_t)(n * CIN + ci) * HW) + y * WW;
    #pragma unroll
    for (int j = 0; j < 14; ++j) {           // 56 floats, per-lane contiguous stream
        const float4 v = ((const float4*)src)[j];
        t[(4 * j + 0) * CIN + ci] = (unsigned short)(__float_as_uint(v.x) >> 16);
        t[(4 * j + 1) * CIN + ci] = (unsigned short)(__float_as_uint(v.y) >> 16);
        t[(4 * j + 2) * CIN + ci] = (unsigned short)(__float_as_uint(v.z) >> 16);
        t[(4 * j + 3) * CIN + ci] = (unsigned short)(__float_as_uint(v.w) >> 16);
    }

    // halo: left/right column of this row, plus full top/bottom rows from edge blocks
    const uint4 z = make_uint4(0, 0, 0, 0);
    if (ci < 32) {
        const int side = ci >> 4;            // 0 = x'=0, 1 = x'=57
        const int j    = ci & 15;
        ((uint4*)(xp + ((size_t)n * XPIX + (y + 1) * XPW + side * 57) * CIN))[j] = z;
    }
    if (y == 0)
        for (int j = ci; j < 928; j += 128)  // row 0: 58*128 bf16 = 928 uint4
            ((uint4*)(xp + (size_t)n * XPIX * CIN))[j] = z;
    if (y == HH - 1)
        for (int j = ci; j < 928; j += 128)  // row 57
            ((uint4*)(xp + ((size_t)n * XPIX + 57 * XPW) * CIN))[j] = z;

    __syncthreads();

    // coalesced interior write: 56 pixels * 256 B contiguous = 896 uint4
    uint4* dst = (uint4*)(xp + ((size_t)n * XPIX + (y + 1) * XPW + 1) * CIN);
    const uint4* lsrc = (const uint4*)t;
    #pragma unroll
    for (int j = 0; j < 7; ++j)
        dst[j * 128 + ci] = lsrc[j * 128 + ci];
}

// ---- pre-pass 2: w (co,ci,3,3) f32 -> Wt[tap][co][ci] bf16
__global__ __launch_bounds__(256) void prep_w(const float* __restrict__ w,
                                              __hip_bfloat16* __restrict__ wt) {
    const int co = blockIdx.x * 2 + (threadIdx.x >> 7);
    const int ci = threadIdx.x & 127;
    const float* src = w + (size_t)(co * CIN + ci) * 9;
    #pragma unroll
    for (int tp = 0; tp < 9; ++tp)
        wt[(size_t)tp * (COUT * CIN) + co * CIN + ci] = __float2bfloat16(src[tp]);
}

// ---- main: implicit GEMM over taps, BK=128 (full ci per tap)
__global__ __launch_bounds__(256) void conv_main(
    const char* __restrict__ xpb,
    const char* __restrict__ wtb,
    const float* __restrict__ bias,
    float* __restrict__ out)
{
    // 128 rows x 256 B (16 segs of 16 B); LDS seg s of row R holds global seg s^(R&15)
    __shared__ __align__(16) char Alds[32768];
    __shared__ __align__(16) char Blds[32768];

    const int tid  = threadIdx.x;
    const int l    = tid & 63;
    const int wv   = tid >> 6;
    const int wm   = wv & 1;
    const int wn   = wv >> 1;
    const int l15  = l & 15;
    const int quad = l >> 4;

    // XCD-pair swizzle: blocks idx and idx+8 (same XCD under %8 round-robin) share bn.
    const int idx = blockIdx.x;
    const int bm  = (idx >> 3) & 1;
    const int bn  = (idx >> 4) * 8 + (idx & 7);
    const int pbase  = bn * 128;
    const int cobase = bm * 128;

    // staging: wave-chunk c = wv*8+j covers rows 4c..4c+3; lane -> row 4c+(l>>4),
    // LDS seg l&15, global seg (l&15)^(row&15). 8 chunks/thread per operand.
    unsigned aoff[8], boff[8];
    #pragma unroll
    for (int j = 0; j < 8; ++j) {
        const int c    = wv * 8 + j;
        const int row  = 4 * c + (l >> 4);
        const int gseg = (l & 15) ^ (row & 15);
        aoff[j] = (unsigned)((cobase + row) * 256 + gseg * 16);
        const int p   = pbase + row;
        const int n   = p / HW;
        const int rem = p - n * HW;
        const int y   = rem / WW;
        const int x   = rem - y * WW;
        boff[j] = (unsigned)((n * XPIX + y * XPW + x) * 256 + gseg * 16);
    }

    f32x4 acc[4][4];
    #pragma unroll
    for (int i = 0; i < 4; ++i)
        #pragma unroll
        for (int j = 0; j < 4; ++j)
            acc[i][j] = (f32x4){0.f, 0.f, 0.f, 0.f};

    #pragma unroll
    for (int t = 0; t < 9; ++t) {
        const int r = t / 3;
        const int s = t - 3 * r;
        const unsigned wo = (unsigned)(t * (COUT * CIN * 2));        // Wt tap plane
        const unsigned bo = (unsigned)((r * XPW + s) * 256);         // xpad tap shift

        __syncthreads();
        #pragma unroll
        for (int j = 0; j < 8; ++j) {
            const int c = wv * 8 + j;
            GLD16(wtb + wo + aoff[j], Alds + c * 1024);
            GLD16(xpb + bo + boff[j], Blds + c * 1024);
        }
        __syncthreads();

        #pragma unroll
        for (int kg = 0; kg < 4; ++kg) {
            bf16x8 af[4], bfr[4];
            #pragma unroll
            for (int mt = 0; mt < 4; ++mt) {
                const int row  = wm * 64 + mt * 16 + l15;
                const int segl = (kg * 4 + quad) ^ l15;              // row&15 == l15
                af[mt] = *(const bf16x8*)(Alds + row * 256 + segl * 16);
            }
            #pragma unroll
            for (int nt = 0; nt < 4; ++nt) {
                const int row  = wn * 64 + nt * 16 + l15;
                const int segl = (kg * 4 + quad) ^ l15;
                bfr[nt] = *(const bf16x8*)(Blds + row * 256 + segl * 16);
            }
            #pragma unroll
            for (int mt = 0; mt < 4; ++mt)
                #pragma unroll
                for (int nt = 0; nt < 4; ++nt)
                    acc[mt][nt] = __builtin_amdgcn_mfma_f32_16x16x32_bf16(
                        af[mt], bfr[nt], acc[mt][nt], 0, 0, 0);
        }
    }

    // epilogue: D[m = quad*4+reg][n = l15]; out (N, C_out, H, W)
    #pragma unroll
    for (int nt = 0; nt < 4; ++nt) {
        const int pp = pbase + wn * 64 + nt * 16 + l15;
        const int n2 = pp / HW;
        const int r2 = pp - n2 * HW;
        float* ob = out + (size_t)n2 * (COUT * HW) + r2;
        #pragma unroll
        for (int mt = 0; mt < 4; ++mt) {
            const int co = cobase + wm * 64 + mt * 16 + quad * 4;
            const float4 bv = *(const float4*)(bias + co);
            f32x4 a = acc[mt][nt];
            ob[(size_t)(co + 0) * HW] = a[0] + bv.x;
            ob[(size_t)(co + 1) * HW] = a[1] + bv.y;
            ob[(size_t)(co + 2) * HW] = a[2] + bv.z;
            ob[(size_t)(co + 3) * HW] = a[3] + bv.w;
        }
    }
}

extern "C" void kernel_launch(void* const* d_in, const int* in_sizes, int n_in,
                              void* d_out, int out_size, void* d_ws, size_t ws_size,
                              hipStream_t stream) {
    const float* x = (const float*)d_in[0];
    const float* w = (const float*)d_in[1];
    const float* b = (const float*)d_in[2];
    char* ws = (char*)d_ws;                      // needs >= 28.2 MB
    __hip_bfloat16* xp = (__hip_bfloat16*)ws;
    __hip_bfloat16* wt = (__hip_bfloat16*)(ws + WT_OFF);

    prep_x<<<dim3(NIMG * HH), dim3(128), 0, stream>>>(x, xp);
    prep_w<<<dim3(128), dim3(256), 0, stream>>>(w, wt);
    conv_main<<<dim3((NP / 128) * 2), dim3(256), 0, stream>>>(
        (const char*)xp, (const char*)wt, b, (float*)d_out);
}